// Round 1
// baseline (604.887 us; speedup 1.0000x reference)
//
#include <hip/hip_runtime.h>

#define DD 1024
#define HALO 32
#define LDSN (DD + 2 * HALO)
#define HALF_DT_F 0.05f
#define CG_ITERS_N 20

// Block-wide sum over 256 threads (4 waves of 64).
__device__ __forceinline__ float block_sum(float v, float* red, int lane, int wave) {
#pragma unroll
    for (int m = 32; m >= 1; m >>= 1)
        v += __shfl_xor(v, m, 64);
    __syncthreads();                 // protect previous reads of red
    if (lane == 0) red[wave] = v;
    __syncthreads();
    return red[0] + red[1] + red[2] + red[3];
}

// H = diag(potential + 10*(w0+w1+w2)) - sum_t cw[t] * (shift(+t) + shift(-t))
// on 4 contiguous elements owned by this thread, reading a 44-float window
// from LDS as 11 aligned float4 loads.
__device__ __forceinline__ void hmat4(const float* __restrict__ ls, int d0,
                                      const float cw[11], const float diag[4],
                                      float out[4]) {
    float win[44];
    const float* base = ls + HALO + d0 - 20;   // (HALO + d0 - 20) % 4 == 0 -> 16B aligned
#pragma unroll
    for (int k = 0; k < 11; ++k) {
        float4 v4 = *reinterpret_cast<const float4*>(base + 4 * k);
        win[4 * k + 0] = v4.x;
        win[4 * k + 1] = v4.y;
        win[4 * k + 2] = v4.z;
        win[4 * k + 3] = v4.w;
    }
    constexpr int taps[11] = {1, 2, 3, 4, 5, 6, 8, 10, 12, 16, 20};
#pragma unroll
    for (int i = 0; i < 4; ++i) {
        float acc = diag[i] * win[20 + i];
#pragma unroll
        for (int j = 0; j < 11; ++j)
            acc -= cw[j] * (win[20 + i - taps[j]] + win[20 + i + taps[j]]);
        out[i] = acc;
    }
}

// Store this thread's 4 contiguous values into the halo'd LDS row image.
__device__ __forceinline__ void store_ld(float* ls, int d0, const float v[4]) {
    float4 v4 = make_float4(v[0], v[1], v[2], v[3]);
    *reinterpret_cast<float4*>(ls + HALO + d0) = v4;
    if (d0 < HALO)                                      // right halo copy of left edge
        *reinterpret_cast<float4*>(ls + HALO + DD + d0) = v4;
    if (d0 >= DD - HALO)                                // left halo copy of right edge
        *reinterpret_cast<float4*>(ls + d0 - DD + HALO) = v4;
}

__global__ void __launch_bounds__(256)
cayley_kernel(const float* __restrict__ psi_r, const float* __restrict__ psi_i,
              const float* __restrict__ alpha, const float* __restrict__ sw,
              const float* __restrict__ potential, float* __restrict__ out) {
    __shared__ __align__(16) float ls_r[LDSN];
    __shared__ __align__(16) float ls_i[LDSN];
    __shared__ float red[4];

    const int row = blockIdx.x;
    const int t = threadIdx.x;
    const int d0 = t << 2;
    const int lane = t & 63;
    const int wave = t >> 6;

    const float w0 = sw[0], w1 = sw[1], w2 = sw[2];
    float cw[11];
    cw[0] = w0;                // tap 1
    cw[1] = w0 + w1;           // tap 2
    cw[2] = w0;                // tap 3
    cw[3] = w0 + w1 + w2;      // tap 4
    cw[4] = w0;                // tap 5
    cw[5] = w1;                // tap 6
    cw[6] = w1 + w2;           // tap 8
    cw[7] = w1;                // tap 10
    cw[8] = w2;                // tap 12
    cw[9] = w2;                // tap 16
    cw[10] = w2;               // tap 20
    const float dadd = 10.0f * (w0 + w1 + w2);

    const float4 pr4 = *reinterpret_cast<const float4*>(psi_r + (size_t)row * DD + d0);
    const float4 pi4 = *reinterpret_cast<const float4*>(psi_i + (size_t)row * DD + d0);
    const float4 al4 = *reinterpret_cast<const float4*>(alpha + d0);
    const float4 po4 = *reinterpret_cast<const float4*>(potential + d0);

    float prv[4] = {pr4.x, pr4.y, pr4.z, pr4.w};
    float piv[4] = {pi4.x, pi4.y, pi4.z, pi4.w};
    float alv[4] = {al4.x, al4.y, al4.z, al4.w};
    float diag[4] = {po4.x + dadd, po4.y + dadd, po4.z + dadd, po4.w + dadd};

    // --- intensity + row mean ---
    float inten[4];
    float isum = 0.f;
#pragma unroll
    for (int i = 0; i < 4; ++i) {
        inten[i] = prv[i] * prv[i] + piv[i] * piv[i];
        isum += inten[i];
    }
    const float tot = block_sum(isum, red, lane, wave);
    const float inv_mean = 1.0f / (tot * (1.0f / DD) + 1e-8f);

    // --- nonlinear phase rotation ---
    float rotr[4], roti[4];
#pragma unroll
    for (int i = 0; i < 4; ++i) {
        const float ph = alv[i] * (inten[i] * inv_mean);
        float s, c;
        sincosf(ph, &s, &c);
        rotr[i] = prv[i] * c - piv[i] * s;
        roti[i] = prv[i] * s + piv[i] * c;
    }

    store_ld(ls_r, d0, rotr);
    store_ld(ls_i, d0, roti);
    __syncthreads();

    // --- rhs = (I - i*dt/2*H) rot ---
    float Hr[4], Hi[4];
    hmat4(ls_r, d0, cw, diag, Hr);
    hmat4(ls_i, d0, cw, diag, Hi);

    float rr[4], ri[4], pr_[4], pi_[4];
    float xr[4] = {0.f, 0.f, 0.f, 0.f};
    float xi[4] = {0.f, 0.f, 0.f, 0.f};
    float rsum = 0.f;
#pragma unroll
    for (int i = 0; i < 4; ++i) {
        rr[i] = rotr[i] + HALF_DT_F * Hi[i];
        ri[i] = roti[i] - HALF_DT_F * Hr[i];
        pr_[i] = rr[i];
        pi_[i] = ri[i];
        rsum += rr[i] * rr[i] + ri[i] * ri[i];
    }
    float rs = block_sum(rsum, red, lane, wave);  // barriers also fence hmat4 reads

    store_ld(ls_r, d0, pr_);
    store_ld(ls_i, d0, pi_);
    __syncthreads();

    // --- CG, fixed 20 iterations ---
    for (int it = 0; it < CG_ITERS_N; ++it) {
        hmat4(ls_r, d0, cw, diag, Hr);
        hmat4(ls_i, d0, cw, diag, Hi);
        float Apr[4], Api[4];
        float pap = 0.f;
#pragma unroll
        for (int i = 0; i < 4; ++i) {
            Apr[i] = pr_[i] - HALF_DT_F * Hi[i];
            Api[i] = pi_[i] + HALF_DT_F * Hr[i];
            pap += pr_[i] * Apr[i] + pi_[i] * Api[i];
        }
        const float pAp = block_sum(pap, red, lane, wave);
        const float alr = rs / (pAp + 1e-12f);
        float rnew = 0.f;
#pragma unroll
        for (int i = 0; i < 4; ++i) {
            xr[i] += alr * pr_[i];
            xi[i] += alr * pi_[i];
            rr[i] -= alr * Apr[i];
            ri[i] -= alr * Api[i];
            rnew += rr[i] * rr[i] + ri[i] * ri[i];
        }
        const float rs_new = block_sum(rnew, red, lane, wave);
        const float beta = rs_new / (rs + 1e-12f);
        rs = rs_new;
#pragma unroll
        for (int i = 0; i < 4; ++i) {
            pr_[i] = rr[i] + beta * pr_[i];
            pi_[i] = ri[i] + beta * pi_[i];
        }
        // All hmat4 reads of the old p are fenced by the two block_sum barriers above.
        store_ld(ls_r, d0, pr_);
        store_ld(ls_i, d0, pi_);
        __syncthreads();
    }

    // --- write x as [.., D, 2] real pairs ---
    float* op = out + ((size_t)row * DD + d0) * 2;
    *reinterpret_cast<float4*>(op) = make_float4(xr[0], xi[0], xr[1], xi[1]);
    *reinterpret_cast<float4*>(op + 4) = make_float4(xr[2], xi[2], xr[3], xi[3]);
}

extern "C" void kernel_launch(void* const* d_in, const int* in_sizes, int n_in,
                              void* d_out, int out_size, void* d_ws, size_t ws_size,
                              hipStream_t stream) {
    const float* psi_r = (const float*)d_in[0];
    const float* psi_i = (const float*)d_in[1];
    const float* alpha = (const float*)d_in[2];
    const float* sw = (const float*)d_in[3];
    const float* pot = (const float*)d_in[4];
    float* out = (float*)d_out;
    const int rows = in_sizes[0] / DD;  // B*S = 8192
    cayley_kernel<<<dim3(rows), dim3(256), 0, stream>>>(psi_r, psi_i, alpha, sw, pot, out);
}